// Round 4
// baseline (1427.589 us; speedup 1.0000x reference)
//
#include <hip/hip_runtime.h>

typedef _Float16 f16;
typedef _Float16 f16x8 __attribute__((ext_vector_type(8)));
typedef _Float16 f16x4 __attribute__((ext_vector_type(4)));
typedef float f32x4 __attribute__((ext_vector_type(4)));

#define NCAM 6
#define CINF 512
#define MIDC 256
#define DB   112
#define HH   32
#define WW   88
#define PH   34
#define PW   90
#define NPOS (HH*WW)       /* 2816 */
#define PT64 44            /* 64-pos tiles per cam; 264 ptiles total = 8 XCD x 33 */

// ---- workspace layout (bytes) ----
#define O_GATE   0L
#define O_WFRED  6144L
#define O_WFBB   2365440L
#define O_WFDP   9443328L
#define O_XP0    9508864L
#define O_X1     28309504L
#define O_DP     28309504L    /* overlays X1; written by depth conv after X1's last read */
#define O_X2     37709824L
#define O_X3     47110144L
/* end: 56510464 */

// ---------------- halo-only zeroing of the 4 padded NHWC buffers ----------------
__global__ void halo_zero_kernel(f16* __restrict__ xp0, f16* __restrict__ X1,
                                 f16* __restrict__ X2, f16* __restrict__ X3) {
  int idx = blockIdx.x * 256 + threadIdx.x;       // one 16B chunk each
  f16* base; int C, rem;
  if (idx < 93696) { base = xp0; C = 512; rem = idx; }
  else {
    int k = idx - 93696;
    int bsel = k / 46848;
    if (bsel >= 3) return;
    rem = k - bsel * 46848; C = 256;
    base = (bsel == 0) ? X1 : (bsel == 1) ? X2 : X3;
  }
  int chunks = C >> 3;
  int cell = rem / chunks, cc = rem - cell * chunks;
  int cam = cell / 244, p = cell - cam * 244;
  int hh, ww;
  if (p < 90)       { hh = 0;  ww = p; }
  else if (p < 180) { hh = 33; ww = p - 90; }
  else { int q = p - 180; hh = 1 + (q >> 1); ww = (q & 1) * 89; }
  long o = ((long)(cam * PH + hh) * PW + ww) * C + cc * 8;
  f16x8 z = {0,0,0,0,0,0,0,0};
  *(f16x8*)(base + o) = z;
}

// ---------------- weights -> chunk-major per-lane A-fragment order ----------------
// dst idx = ((((g*TAPS+tap)*CPT+cc)*64 + lane)*64) + s*32 + mi*8 + j
// co = g*64+mi*16+(lane&15), ci = cc*64+s*32+(lane>>4)*8+j, src OIHW[co][ci][tap]
// -> each lane's chunk data is 128B contiguous (one base, imm offsets, L1-friendly)
__global__ void wfrag_kernel(const float* __restrict__ src, const float* __restrict__ scale,
                             f16* __restrict__ dst, int TAPS, int CI, int CO_SRC,
                             long per, long total) {
  long i = (long)blockIdx.x * blockDim.x + threadIdx.x;
  long stride = (long)gridDim.x * blockDim.x;
  int CPT = CI >> 6;
  for (; i < total; i += stride) {
    int conv = (int)(i / per);
    long rem = i - (long)conv * per;
    int j = (int)(rem & 7);
    int mi = (int)((rem >> 3) & 3);
    int s = (int)((rem >> 5) & 1);
    int lane = (int)((rem >> 6) & 63);
    long b = rem >> 12;
    int cc = (int)(b % CPT);
    long b2 = b / CPT;
    int tap = (int)(b2 % TAPS);
    int g = (int)(b2 / TAPS);
    int co = g * 64 + mi * 16 + (lane & 15);
    int ci = cc * 64 + s * 32 + (lane >> 4) * 8 + j;
    float v = 0.f;
    if (co < CO_SRC) {
      v = src[(long)conv * CO_SRC * CI * TAPS + ((long)co * CI + ci) * TAPS + tap];
      if (scale) v *= scale[conv * CO_SRC + co];
    }
    dst[i] = (f16)v;
  }
}

// ---------------- img NCHW f32 -> padded NHWC f16 ----------------
__global__ void img_trans_kernel(const float* __restrict__ src, f16* __restrict__ dst) {
  __shared__ float tile[32][33];
  int tx = threadIdx.x & 31, ty = threadIdx.x >> 5;
  int wt = blockIdx.x % 3, ct = blockIdx.x / 3;
  int h = blockIdx.y, n = blockIdx.z;
  int w0 = wt * 32, c0 = ct * 32;
  #pragma unroll
  for (int i = 0; i < 4; ++i) {
    int cl = ty + i * 8;
    int w = w0 + tx;
    float v = 0.f;
    if (w < WW) v = src[((long)(n * CINF + c0 + cl) * HH + h) * WW + w];
    tile[cl][tx] = v;
  }
  __syncthreads();
  #pragma unroll
  for (int i = 0; i < 4; ++i) {
    int wl = ty + i * 8;
    int w = w0 + wl;
    if (w < WW)
      dst[((long)((n * PH + h + 1) * PW + (w + 1))) * CINF + c0 + tx] = (f16)tile[tx][wl];
  }
}

// ---------------- SE gate ----------------
__global__ void se_gate_kernel(const float* __restrict__ intr,
                               const float* __restrict__ w1, const float* __restrict__ b1,
                               const float* __restrict__ w2, const float* __restrict__ b2,
                               const float* __restrict__ rw, const float* __restrict__ rb,
                               const float* __restrict__ ew, const float* __restrict__ eb,
                               float* __restrict__ gate) {
  __shared__ float sps;
  __shared__ float h1[MIDC];
  __shared__ float h2[MIDC];
  __shared__ float tt[MIDC];
  int n = blockIdx.x, c = threadIdx.x;
  if (c == 0) {
    float a[4][8];
    for (int i = 0; i < 4; ++i)
      for (int j = 0; j < 4; ++j) {
        a[i][j] = intr[n * 16 + i * 4 + j];
        a[i][4 + j] = (i == j) ? 1.f : 0.f;
      }
    for (int col = 0; col < 4; ++col) {
      int piv = col;
      for (int r2 = col + 1; r2 < 4; ++r2)
        if (fabsf(a[r2][col]) > fabsf(a[piv][col])) piv = r2;
      if (piv != col)
        for (int j = 0; j < 8; ++j) { float tv = a[col][j]; a[col][j] = a[piv][j]; a[piv][j] = tv; }
      float invp = 1.f / a[col][col];
      for (int j = 0; j < 8; ++j) a[col][j] *= invp;
      for (int r2 = 0; r2 < 4; ++r2)
        if (r2 != col) {
          float f = a[r2][col];
          for (int j = 0; j < 8; ++j) a[r2][j] -= f * a[col][j];
        }
    }
    float i00 = a[0][4], i11 = a[1][5];
    sps = sqrtf(i00 * i00 + i11 * i11) * 1000.f;
  }
  __syncthreads();
  float sp = sps;
  h1[c] = fmaxf(sp * w1[c] + b1[c], 0.f);
  __syncthreads();
  float acc = b2[c];
  for (int j = 0; j < MIDC; ++j) acc += h1[j] * w2[j * MIDC + c];
  h2[c] = acc;
  __syncthreads();
  acc = rb[c];
  for (int j = 0; j < MIDC; ++j) acc += rw[c * MIDC + j] * h2[j];
  tt[c] = fmaxf(acc, 0.f);
  __syncthreads();
  acc = eb[c];
  for (int j = 0; j < MIDC; ++j) acc += ew[c * MIDC + j] * tt[j];
  gate[n * MIDC + c] = 1.f / (1.f + expf(-acc));
}

// ---------------- MFMA implicit-GEMM conv v4: BARRIER-FREE K-loop ----------------
// Tile 128co x 64pos, 4 waves (wm: co-half, wn: pos-half), wave 64co x 32pos.
// NO LDS, NO __syncthreads in K-loop: A streams global->VGPR (chunk-major layout,
// 128B/lane contiguous), B fragments load global->VGPR per lane (16x64B segments
// per instr). Fully-unrolled flat loop => compiler pipelines with fine vmcnt(N).
// XCD swizzle: bid&7 selects a 33-ptile slice so each XCD's L2 holds weights+x-slice.
// MODE 0: relu(acc+b)*gate; 1: relu(acc+b); 2: relu(acc+b+res); 3: logits+softmax.
template<int MODE, int CIN_T, int TAPS>
__global__ __launch_bounds__(256, 2)
void conv_mfma(const f16* __restrict__ X, const f16* __restrict__ Wf,
               const float* __restrict__ bias, const float* __restrict__ gate,
               const f16* __restrict__ res, f16* __restrict__ Yf16,
               float* __restrict__ dpout, int co_tiles) {
  constexpr int CPT = CIN_T / 64;     // 64-ci chunks per tap
  constexpr int NCH = TAPS * CPT;
  extern __shared__ __align__(16) char smem[];   // used only by MODE 3 epilogue

  const int t = threadIdx.x;
  const int wv = t >> 6, ln = t & 63, lm = ln & 15, quad = ln >> 4;
  const int wm = wv >> 1, wn = wv & 1;

  // XCD-aware swizzle: 264 ptiles = 8 XCDs x 33
  const int bid = blockIdx.x;
  const int xcd = bid & 7;
  const int li = bid >> 3;
  const int co_tile = li / 33;
  const int lp = li - co_tile * 33;
  const int ptile = xcd * 33 + lp;
  const int cam = ptile / PT64;
  const int pbase = (ptile % PT64) * 64;

  // B per-lane base pointers (ni = 0,1): pos = pbase + wn*32 + ni*16 + lm
  const f16* bp[2];
  #pragma unroll
  for (int ni = 0; ni < 2; ++ni) {
    int pos = pbase + wn * 32 + ni * 16 + lm;
    int hh = pos / WW, w2 = pos - hh * WW;
    bp[ni] = X + ((long)((cam * PH + hh + 1) * PW + (w2 + 1))) * CIN_T + quad * 8;
  }
  // A stream base for this wave's 64-co group (wm pair shares -> L1 hits)
  const int g = co_tile * 2 + wm;
  const f16* wa = Wf + ((long)g * TAPS * CPT) * 4096 + ln * 64;

  f32x4 acc[4][2];
  #pragma unroll
  for (int mi = 0; mi < 4; ++mi)
    #pragma unroll
    for (int ni = 0; ni < 2; ++ni)
      #pragma unroll
      for (int r = 0; r < 4; ++r) acc[mi][ni][r] = 0.f;

  #pragma unroll
  for (int c = 0; c < NCH; ++c) {
    const int tap = c / CPT;           // compile-time after full unroll
    const int cc = c - tap * CPT;
    const int dy = (TAPS == 9) ? (tap / 3 - 1) : 0;
    const int dx = (TAPS == 9) ? (tap % 3 - 1) : 0;
    const int boff = (dy * PW + dx) * CIN_T + cc * 64;

    f16x8 a[8];
    const f16* ab = wa + (long)c * 4096;
    #pragma unroll
    for (int s = 0; s < 2; ++s)
      #pragma unroll
      for (int mi = 0; mi < 4; ++mi)
        a[s * 4 + mi] = *(const f16x8*)(ab + s * 32 + mi * 8);

    f16x8 b[4];
    #pragma unroll
    for (int s = 0; s < 2; ++s)
      #pragma unroll
      for (int ni = 0; ni < 2; ++ni)
        b[s * 2 + ni] = *(const f16x8*)(bp[ni] + boff + s * 32);

    #pragma unroll
    for (int s = 0; s < 2; ++s)
      #pragma unroll
      for (int mi = 0; mi < 4; ++mi)
        #pragma unroll
        for (int ni = 0; ni < 2; ++ni)
          acc[mi][ni] = __builtin_amdgcn_mfma_f32_16x16x32_f16(a[s * 4 + mi], b[s * 2 + ni], acc[mi][ni], 0, 0, 0);
  }

  if (MODE == 3) {
    // ---- fused bias + softmax over 112 bins ----
    float* Lt = (float*)smem;                       // [64][113] f32
    #pragma unroll
    for (int mi = 0; mi < 4; ++mi) {
      int co_l = wm * 64 + mi * 16 + quad * 4;
      if (co_l >= DB) continue;                     // skips only (wm=1,mi=3)
      float4 b4 = *(const float4*)(bias + co_l);
      #pragma unroll
      for (int ni = 0; ni < 2; ++ni) {
        int pl = wn * 32 + ni * 16 + lm;
        #pragma unroll
        for (int r = 0; r < 4; ++r)
          Lt[pl * 113 + co_l + r] = acc[mi][ni][r] + ((float*)&b4)[r];
      }
    }
    __syncthreads();
    int p = t >> 2, q = t & 3;
    const float* rowp = Lt + p * 113 + q * 28;
    float m = -1e30f;
    #pragma unroll
    for (int i = 0; i < 28; ++i) m = fmaxf(m, rowp[i]);
    m = fmaxf(m, __shfl_xor(m, 1));
    m = fmaxf(m, __shfl_xor(m, 2));
    float e[28], ssum = 0.f;
    #pragma unroll
    for (int i = 0; i < 28; ++i) { e[i] = __expf(rowp[i] - m); ssum += e[i]; }
    ssum += __shfl_xor(ssum, 1);
    ssum += __shfl_xor(ssum, 2);
    float inv = 1.f / ssum;
    float* o = dpout + ((long)(cam * NPOS + pbase + p)) * DB + q * 28;
    #pragma unroll
    for (int i = 0; i < 28; ++i) o[i] = e[i] * inv;
    return;
  }

  // ---- epilogue: direct stores from acc ----
  float4 b4[4], g4[4];
  #pragma unroll
  for (int mi = 0; mi < 4; ++mi) {
    int co_g = co_tile * 128 + wm * 64 + mi * 16 + quad * 4;
    b4[mi] = *(const float4*)(bias + co_g);
    if (MODE == 0) g4[mi] = *(const float4*)(gate + cam * MIDC + co_g);
  }
  #pragma unroll
  for (int ni = 0; ni < 2; ++ni) {
    int pos = pbase + wn * 32 + ni * 16 + lm;
    int hh = pos / WW, w2 = pos - hh * WW;
    long ob = ((long)((cam * PH + hh + 1) * PW + (w2 + 1))) * MIDC + co_tile * 128;
    #pragma unroll
    for (int mi = 0; mi < 4; ++mi) {
      int co_l = wm * 64 + mi * 16 + quad * 4;
      float v[4];
      #pragma unroll
      for (int r = 0; r < 4; ++r) {
        float y = acc[mi][ni][r] + ((float*)&b4[mi])[r];
        if (MODE == 0) y = fmaxf(y, 0.f) * ((float*)&g4[mi])[r];
        else if (MODE == 1) y = fmaxf(y, 0.f);
        v[r] = y;
      }
      if (MODE == 2) {
        f16x4 rv = *(const f16x4*)(res + ob + co_l);
        f16x4 o;
        #pragma unroll
        for (int r = 0; r < 4; ++r) o[r] = (f16)fmaxf(v[r] + (float)rv[r], 0.f);
        *(f16x4*)(Yf16 + ob + co_l) = o;
      } else {
        f16x4 o;
        #pragma unroll
        for (int r = 0; r < 4; ++r) o[r] = (f16)v[r];
        *(f16x4*)(Yf16 + ob + co_l) = o;
      }
    }
  }
}

// ---------------- trilinear grid sample + camera sum + normalize ----------------
__global__ void sample_kernel(const float* __restrict__ grid, const float* __restrict__ dp,
                              float* __restrict__ out) {
  int v = blockIdx.x * blockDim.x + threadIdx.x;
  if (v >= 128 * 128 * 16) return;
  int vz = v & 15, vy = (v >> 4) & 127, vx = v >> 11;
  float agg = 0.f, msk = 0.f;
  #pragma unroll 1
  for (int n = 0; n < NCAM; ++n) {
    long gb = ((long)((n * 128 + vx) * 128 + vy) * 16 + vz) * 3;
    float gx = grid[gb], gy = grid[gb + 1], gz = grid[gb + 2];
    float ix = ((gx + 1.f) * (float)WW - 1.f) * 0.5f;
    float iy = ((gy + 1.f) * (float)HH - 1.f) * 0.5f;
    float iz = ((gz + 1.f) * (float)DB - 1.f) * 0.5f;
    float xf = floorf(ix), yf = floorf(iy), zf = floorf(iz);
    float fx = ix - xf, fy = iy - yf, fz = iz - zf;
    int x0 = (int)xf, y0 = (int)yf, z0 = (int)zf;
    float wxa[2] = {1.f - fx, fx};
    float wya[2] = {1.f - fy, fy};
    float wza[2] = {1.f - fz, fz};
    #pragma unroll
    for (int dy2 = 0; dy2 < 2; ++dy2) {
      int y = y0 + dy2;
      bool vyb = (y >= 0) && (y < HH);
      int yc = y < 0 ? 0 : (y > HH - 1 ? HH - 1 : y);
      #pragma unroll
      for (int dx2 = 0; dx2 < 2; ++dx2) {
        int x = x0 + dx2;
        bool vxb = (x >= 0) && (x < WW);
        int xc = x < 0 ? 0 : (x > WW - 1 ? WW - 1 : x);
        float wxy = wxa[dx2] * wya[dy2];
        const float* base = dp + ((long)((n * HH + yc) * WW + xc)) * DB;
        #pragma unroll
        for (int dz2 = 0; dz2 < 2; ++dz2) {
          int z = z0 + dz2;
          bool vzb = (z >= 0) && (z < DB);
          int zc = z < 0 ? 0 : (z > DB - 1 ? DB - 1 : z);
          float wgt = wxy * wza[dz2];
          if (vxb && vyb && vzb) {
            msk += wgt;
            agg += wgt * base[zc];
          }
        }
      }
    }
  }
  out[v] = (msk > 0.f) ? (agg / msk) : agg;
}

extern "C" void kernel_launch(void* const* d_in, const int* in_sizes, int n_in,
                              void* d_out, int out_size, void* d_ws, size_t ws_size,
                              hipStream_t stream) {
  const float* img   = (const float*)d_in[0];
  const float* intr  = (const float*)d_in[1];
  const float* grid  = (const float*)d_in[2];
  const float* red_w = (const float*)d_in[3];
  const float* red_s = (const float*)d_in[4];
  const float* red_b = (const float*)d_in[5];
  const float* w1    = (const float*)d_in[6];
  const float* b1    = (const float*)d_in[7];
  const float* w2    = (const float*)d_in[8];
  const float* b2    = (const float*)d_in[9];
  const float* rw    = (const float*)d_in[10];
  const float* rb    = (const float*)d_in[11];
  const float* ew    = (const float*)d_in[12];
  const float* eb    = (const float*)d_in[13];
  const float* bb_w  = (const float*)d_in[14];
  const float* bb_s  = (const float*)d_in[15];
  const float* bb_b  = (const float*)d_in[16];
  const float* dp_w  = (const float*)d_in[17];
  const float* dp_b  = (const float*)d_in[18];
  float* out = (float*)d_out;

  char* ws = (char*)d_ws;
  float* gate = (float*)(ws + O_GATE);
  f16* wfred  = (f16*)(ws + O_WFRED);
  f16* wfbb   = (f16*)(ws + O_WFBB);
  f16* wfdp   = (f16*)(ws + O_WFDP);
  f16* xp0    = (f16*)(ws + O_XP0);
  f16* X1     = (f16*)(ws + O_X1);
  f16* X2     = (f16*)(ws + O_X2);
  f16* X3     = (f16*)(ws + O_X3);
  float* dpb  = (float*)(ws + O_DP);

  halo_zero_kernel<<<915, 256, 0, stream>>>(xp0, X1, X2, X3);
  {
    long per = 4L * 9 * 8 * 4096, total = per;
    wfrag_kernel<<<2048, 256, 0, stream>>>(red_w, red_s, wfred, 9, 512, 256, per, total);
  }
  {
    long per = 4L * 9 * 4 * 4096, total = 6 * per;
    wfrag_kernel<<<4096, 256, 0, stream>>>(bb_w, bb_s, wfbb, 9, 256, 256, per, total);
  }
  {
    long per = 2L * 1 * 4 * 4096, total = per;
    wfrag_kernel<<<128, 256, 0, stream>>>(dp_w, nullptr, wfdp, 1, 256, 112, per, total);
  }
  img_trans_kernel<<<dim3(48, 32, 6), 256, 0, stream>>>(img, xp0);
  se_gate_kernel<<<6, 256, 0, stream>>>(intr, w1, b1, w2, b2, rw, rb, ew, eb, gate);

  const long WCH = 4L * 9 * 4 * 4096;  // per-conv fragment-weight stride (f16)

  conv_mfma<0, 512, 9><<<528, 256, 0, stream>>>(xp0, wfred, red_b, gate, nullptr, X1, nullptr, 2);

  conv_mfma<1, 256, 9><<<528, 256, 0, stream>>>(X1, wfbb + 0 * WCH, bb_b + 0 * 256, nullptr, nullptr, X2, nullptr, 2);
  conv_mfma<2, 256, 9><<<528, 256, 0, stream>>>(X2, wfbb + 1 * WCH, bb_b + 1 * 256, nullptr, X1, X3, nullptr, 2);
  conv_mfma<1, 256, 9><<<528, 256, 0, stream>>>(X3, wfbb + 2 * WCH, bb_b + 2 * 256, nullptr, nullptr, X2, nullptr, 2);
  conv_mfma<2, 256, 9><<<528, 256, 0, stream>>>(X2, wfbb + 3 * WCH, bb_b + 3 * 256, nullptr, X3, X1, nullptr, 2);
  conv_mfma<1, 256, 9><<<528, 256, 0, stream>>>(X1, wfbb + 4 * WCH, bb_b + 4 * 256, nullptr, nullptr, X2, nullptr, 2);
  conv_mfma<2, 256, 9><<<528, 256, 0, stream>>>(X2, wfbb + 5 * WCH, bb_b + 5 * 256, nullptr, X1, X3, nullptr, 2);

  // depth 1x1 conv with fused softmax -> dp f32
  conv_mfma<3, 256, 1><<<264, 256, 28928, stream>>>(X3, wfdp, dp_b, nullptr, nullptr, nullptr, dpb, 1);

  sample_kernel<<<1024, 256, 0, stream>>>(grid, dpb, out);
}

// Round 5
// 1418.611 us; speedup vs baseline: 1.0063x; 1.0063x over previous
//
#include <hip/hip_runtime.h>

typedef _Float16 f16;
typedef _Float16 f16x8 __attribute__((ext_vector_type(8)));
typedef _Float16 f16x4 __attribute__((ext_vector_type(4)));
typedef float f32x4 __attribute__((ext_vector_type(4)));

#define NCAM 6
#define CINF 512
#define MIDC 256
#define DB   112
#define HH   32
#define WW   88
#define PH   34
#define PW   90
#define NPOS (HH*WW)       /* 2816 */
#define PT64 44            /* 64-pos tiles per cam; 264 ptiles total = 8 XCD x 33 */

// ---- workspace layout (bytes) ----
#define O_GATE   0L
#define O_WFRED  6144L
#define O_WFBB   2365440L
#define O_WFDP   9443328L
#define O_XP0    9508864L
#define O_X1     28309504L
#define O_DP     28309504L    /* f16 dp overlays X1; written by depth conv after X1's last read */
#define O_X2     37709824L
#define O_X3     47110144L
/* end: 56510464 */

// ---------------- halo-only zeroing of the 4 padded NHWC buffers ----------------
__global__ void halo_zero_kernel(f16* __restrict__ xp0, f16* __restrict__ X1,
                                 f16* __restrict__ X2, f16* __restrict__ X3) {
  int idx = blockIdx.x * 256 + threadIdx.x;       // one 16B chunk each
  f16* base; int C, rem;
  if (idx < 93696) { base = xp0; C = 512; rem = idx; }
  else {
    int k = idx - 93696;
    int bsel = k / 46848;
    if (bsel >= 3) return;
    rem = k - bsel * 46848; C = 256;
    base = (bsel == 0) ? X1 : (bsel == 1) ? X2 : X3;
  }
  int chunks = C >> 3;
  int cell = rem / chunks, cc = rem - cell * chunks;
  int cam = cell / 244, p = cell - cam * 244;
  int hh, ww;
  if (p < 90)       { hh = 0;  ww = p; }
  else if (p < 180) { hh = 33; ww = p - 90; }
  else { int q = p - 180; hh = 1 + (q >> 1); ww = (q & 1) * 89; }
  long o = ((long)(cam * PH + hh) * PW + ww) * C + cc * 8;
  f16x8 z = {0,0,0,0,0,0,0,0};
  *(f16x8*)(base + o) = z;
}

// ---------------- weights -> chunk-major per-lane A-fragment order ----------------
// dst idx = ((((g*TAPS+tap)*CPT+cc)*64 + lane)*64) + s*32 + mi*8 + j
// co = g*64+mi*16+(lane&15), ci = cc*64+s*32+(lane>>4)*8+j, src OIHW[co][ci][tap]
__global__ void wfrag_kernel(const float* __restrict__ src, const float* __restrict__ scale,
                             f16* __restrict__ dst, int TAPS, int CI, int CO_SRC,
                             long per, long total) {
  long i = (long)blockIdx.x * blockDim.x + threadIdx.x;
  long stride = (long)gridDim.x * blockDim.x;
  int CPT = CI >> 6;
  for (; i < total; i += stride) {
    int conv = (int)(i / per);
    long rem = i - (long)conv * per;
    int j = (int)(rem & 7);
    int mi = (int)((rem >> 3) & 3);
    int s = (int)((rem >> 5) & 1);
    int lane = (int)((rem >> 6) & 63);
    long b = rem >> 12;
    int cc = (int)(b % CPT);
    long b2 = b / CPT;
    int tap = (int)(b2 % TAPS);
    int g = (int)(b2 / TAPS);
    int co = g * 64 + mi * 16 + (lane & 15);
    int ci = cc * 64 + s * 32 + (lane >> 4) * 8 + j;
    float v = 0.f;
    if (co < CO_SRC) {
      v = src[(long)conv * CO_SRC * CI * TAPS + ((long)co * CI + ci) * TAPS + tap];
      if (scale) v *= scale[conv * CO_SRC + co];
    }
    dst[i] = (f16)v;
  }
}

// ---------------- img NCHW f32 -> padded NHWC f16 ----------------
__global__ void img_trans_kernel(const float* __restrict__ src, f16* __restrict__ dst) {
  __shared__ float tile[32][33];
  int tx = threadIdx.x & 31, ty = threadIdx.x >> 5;
  int wt = blockIdx.x % 3, ct = blockIdx.x / 3;
  int h = blockIdx.y, n = blockIdx.z;
  int w0 = wt * 32, c0 = ct * 32;
  #pragma unroll
  for (int i = 0; i < 4; ++i) {
    int cl = ty + i * 8;
    int w = w0 + tx;
    float v = 0.f;
    if (w < WW) v = src[((long)(n * CINF + c0 + cl) * HH + h) * WW + w];
    tile[cl][tx] = v;
  }
  __syncthreads();
  #pragma unroll
  for (int i = 0; i < 4; ++i) {
    int wl = ty + i * 8;
    int w = w0 + wl;
    if (w < WW)
      dst[((long)((n * PH + h + 1) * PW + (w + 1))) * CINF + c0 + tx] = (f16)tile[tx][wl];
  }
}

// ---------------- SE gate ----------------
__global__ void se_gate_kernel(const float* __restrict__ intr,
                               const float* __restrict__ w1, const float* __restrict__ b1,
                               const float* __restrict__ w2, const float* __restrict__ b2,
                               const float* __restrict__ rw, const float* __restrict__ rb,
                               const float* __restrict__ ew, const float* __restrict__ eb,
                               float* __restrict__ gate) {
  __shared__ float sps;
  __shared__ float h1[MIDC];
  __shared__ float h2[MIDC];
  __shared__ float tt[MIDC];
  int n = blockIdx.x, c = threadIdx.x;
  if (c == 0) {
    float a[4][8];
    for (int i = 0; i < 4; ++i)
      for (int j = 0; j < 4; ++j) {
        a[i][j] = intr[n * 16 + i * 4 + j];
        a[i][4 + j] = (i == j) ? 1.f : 0.f;
      }
    for (int col = 0; col < 4; ++col) {
      int piv = col;
      for (int r2 = col + 1; r2 < 4; ++r2)
        if (fabsf(a[r2][col]) > fabsf(a[piv][col])) piv = r2;
      if (piv != col)
        for (int j = 0; j < 8; ++j) { float tv = a[col][j]; a[col][j] = a[piv][j]; a[piv][j] = tv; }
      float invp = 1.f / a[col][col];
      for (int j = 0; j < 8; ++j) a[col][j] *= invp;
      for (int r2 = 0; r2 < 4; ++r2)
        if (r2 != col) {
          float f = a[r2][col];
          for (int j = 0; j < 8; ++j) a[r2][j] -= f * a[col][j];
        }
    }
    float i00 = a[0][4], i11 = a[1][5];
    sps = sqrtf(i00 * i00 + i11 * i11) * 1000.f;
  }
  __syncthreads();
  float sp = sps;
  h1[c] = fmaxf(sp * w1[c] + b1[c], 0.f);
  __syncthreads();
  float acc = b2[c];
  for (int j = 0; j < MIDC; ++j) acc += h1[j] * w2[j * MIDC + c];
  h2[c] = acc;
  __syncthreads();
  acc = rb[c];
  for (int j = 0; j < MIDC; ++j) acc += rw[c * MIDC + j] * h2[j];
  tt[c] = fmaxf(acc, 0.f);
  __syncthreads();
  acc = eb[c];
  for (int j = 0; j < MIDC; ++j) acc += ew[c * MIDC + j] * tt[j];
  gate[n * MIDC + c] = 1.f / (1.f + expf(-acc));
}

// ---------------- MFMA implicit-GEMM conv v5: barrier-free, REGISTER-PIPELINED ----------------
// Tile 128co x 64pos, 4 waves, wave 64co x 32pos. No LDS/barriers in K-loop.
// Explicit 2-stage register double-buffer for BOTH A and B: loads for chunk c+1
// are issued before compute(c) (R2-proven pattern), so the compiler keeps 12
// loads in flight across each MFMA burst with fine-grained vmcnt.
// XCD swizzle (bid&7) keeps per-XCD working set ~L2-sized (FETCH 20MB, R4-proven).
// MODE 0: relu(acc+b)*gate; 1: relu(acc+b); 2: relu(acc+b+res); 3: logits+softmax->f16 dp.
template<int MODE, int CIN_T, int TAPS>
__global__ __launch_bounds__(256, 2)
void conv_mfma(const f16* __restrict__ X, const f16* __restrict__ Wf,
               const float* __restrict__ bias, const float* __restrict__ gate,
               const f16* __restrict__ res, f16* __restrict__ Yf16,
               f16* __restrict__ dpout, int co_tiles) {
  constexpr int CPT = CIN_T / 64;     // 64-ci chunks per tap (8 or 4)
  constexpr int LCPT = (CPT == 8) ? 3 : 2;
  constexpr int NCH = TAPS * CPT;     // 72 / 36 / 4 (always even)
  extern __shared__ __align__(16) char smem[];   // used only by MODE 3 epilogue

  const int t = threadIdx.x;
  const int wv = t >> 6, ln = t & 63, lm = ln & 15, quad = ln >> 4;
  const int wm = wv >> 1, wn = wv & 1;

  // XCD-aware swizzle: ptiles sliced 8 x 33
  const int bid = blockIdx.x;
  const int xcd = bid & 7;
  const int li = bid >> 3;
  const int co_tile = li / 33;
  const int lp = li - co_tile * 33;
  const int ptile = xcd * 33 + lp;
  const int cam = ptile / PT64;
  const int pbase = (ptile % PT64) * 64;

  // B per-lane base pointers (ni = 0,1): pos = pbase + wn*32 + ni*16 + lm
  const f16* bp[2];
  #pragma unroll
  for (int ni = 0; ni < 2; ++ni) {
    int pos = pbase + wn * 32 + ni * 16 + lm;
    int hh = pos / WW, w2 = pos - hh * WW;
    bp[ni] = X + ((long)((cam * PH + hh + 1) * PW + (w2 + 1))) * CIN_T + quad * 8;
  }
  // A stream base for this wave's 64-co group (wm pair shares -> L1 hits)
  const int g = co_tile * 2 + wm;
  const f16* wa = Wf + ((long)g * TAPS * CPT) * 4096 + ln * 64;

  f32x4 acc[4][2];
  #pragma unroll
  for (int mi = 0; mi < 4; ++mi)
    #pragma unroll
    for (int ni = 0; ni < 2; ++ni)
      #pragma unroll
      for (int r = 0; r < 4; ++r) acc[mi][ni][r] = 0.f;

  auto loadA = [&](f16x8* a, int c) {
    const f16* ab = wa + (long)c * 4096;
    #pragma unroll
    for (int s = 0; s < 2; ++s)
      #pragma unroll
      for (int mi = 0; mi < 4; ++mi)
        a[s * 4 + mi] = *(const f16x8*)(ab + s * 32 + mi * 8);
  };
  auto loadB = [&](f16x8* b, int c) {
    int tap = c >> LCPT, cc = c & (CPT - 1);
    int dy = (TAPS == 9) ? ((tap < 3) ? -1 : ((tap < 6) ? 0 : 1)) : 0;
    int dx = (TAPS == 9) ? (tap - (dy + 1) * 3 - 1) : 0;
    int boff = (dy * PW + dx) * CIN_T + cc * 64;
    #pragma unroll
    for (int s = 0; s < 2; ++s)
      #pragma unroll
      for (int ni = 0; ni < 2; ++ni)
        b[s * 2 + ni] = *(const f16x8*)(bp[ni] + boff + s * 32);
  };
  auto comp = [&](const f16x8* a, const f16x8* b) {
    #pragma unroll
    for (int s = 0; s < 2; ++s)
      #pragma unroll
      for (int mi = 0; mi < 4; ++mi)
        #pragma unroll
        for (int ni = 0; ni < 2; ++ni)
          acc[mi][ni] = __builtin_amdgcn_mfma_f32_16x16x32_f16(a[s * 4 + mi], b[s * 2 + ni], acc[mi][ni], 0, 0, 0);
  };

  f16x8 aA[8], aB[8], bA[4], bB[4];
  loadA(aA, 0); loadB(bA, 0);
  #pragma unroll 1
  for (int c = 0; c < NCH; c += 2) {
    loadA(aB, c + 1); loadB(bB, c + 1);
    comp(aA, bA);
    if (c + 2 < NCH) { loadA(aA, c + 2); loadB(bA, c + 2); }
    comp(aB, bB);
  }

  if (MODE == 3) {
    // ---- fused bias + softmax over 112 bins -> f16 dp ----
    float* Lt = (float*)smem;                       // [64][113] f32
    #pragma unroll
    for (int mi = 0; mi < 4; ++mi) {
      int co_l = wm * 64 + mi * 16 + quad * 4;
      if (co_l >= DB) continue;                     // skips only (wm=1,mi=3)
      float4 b4 = *(const float4*)(bias + co_l);
      #pragma unroll
      for (int ni = 0; ni < 2; ++ni) {
        int pl = wn * 32 + ni * 16 + lm;
        #pragma unroll
        for (int r = 0; r < 4; ++r)
          Lt[pl * 113 + co_l + r] = acc[mi][ni][r] + ((float*)&b4)[r];
      }
    }
    __syncthreads();
    int p = t >> 2, q = t & 3;
    const float* rowp = Lt + p * 113 + q * 28;
    float m = -1e30f;
    #pragma unroll
    for (int i = 0; i < 28; ++i) m = fmaxf(m, rowp[i]);
    m = fmaxf(m, __shfl_xor(m, 1));
    m = fmaxf(m, __shfl_xor(m, 2));
    float e[28], ssum = 0.f;
    #pragma unroll
    for (int i = 0; i < 28; ++i) { e[i] = __expf(rowp[i] - m); ssum += e[i]; }
    ssum += __shfl_xor(ssum, 1);
    ssum += __shfl_xor(ssum, 2);
    float inv = 1.f / ssum;
    f16* o = dpout + ((long)(cam * NPOS + pbase + p)) * DB + q * 28;
    #pragma unroll
    for (int i = 0; i < 28; ++i) o[i] = (f16)(e[i] * inv);
    return;
  }

  // ---- epilogue: direct stores from acc ----
  float4 b4[4], g4[4];
  #pragma unroll
  for (int mi = 0; mi < 4; ++mi) {
    int co_g = co_tile * 128 + wm * 64 + mi * 16 + quad * 4;
    b4[mi] = *(const float4*)(bias + co_g);
    if (MODE == 0) g4[mi] = *(const float4*)(gate + cam * MIDC + co_g);
  }
  #pragma unroll
  for (int ni = 0; ni < 2; ++ni) {
    int pos = pbase + wn * 32 + ni * 16 + lm;
    int hh = pos / WW, w2 = pos - hh * WW;
    long ob = ((long)((cam * PH + hh + 1) * PW + (w2 + 1))) * MIDC + co_tile * 128;
    #pragma unroll
    for (int mi = 0; mi < 4; ++mi) {
      int co_l = wm * 64 + mi * 16 + quad * 4;
      float v[4];
      #pragma unroll
      for (int r = 0; r < 4; ++r) {
        float y = acc[mi][ni][r] + ((float*)&b4[mi])[r];
        if (MODE == 0) y = fmaxf(y, 0.f) * ((float*)&g4[mi])[r];
        else if (MODE == 1) y = fmaxf(y, 0.f);
        v[r] = y;
      }
      if (MODE == 2) {
        f16x4 rv = *(const f16x4*)(res + ob + co_l);
        f16x4 o;
        #pragma unroll
        for (int r = 0; r < 4; ++r) o[r] = (f16)fmaxf(v[r] + (float)rv[r], 0.f);
        *(f16x4*)(Yf16 + ob + co_l) = o;
      } else {
        f16x4 o;
        #pragma unroll
        for (int r = 0; r < 4; ++r) o[r] = (f16)v[r];
        *(f16x4*)(Yf16 + ob + co_l) = o;
      }
    }
  }
}

// ---------------- trilinear grid sample (f16 dp) + camera sum + normalize ----------------
__global__ void sample_kernel(const float* __restrict__ grid, const f16* __restrict__ dp,
                              float* __restrict__ out) {
  int v = blockIdx.x * blockDim.x + threadIdx.x;
  if (v >= 128 * 128 * 16) return;
  int vz = v & 15, vy = (v >> 4) & 127, vx = v >> 11;
  float agg = 0.f, msk = 0.f;
  #pragma unroll 1
  for (int n = 0; n < NCAM; ++n) {
    long gb = ((long)((n * 128 + vx) * 128 + vy) * 16 + vz) * 3;
    float gx = grid[gb], gy = grid[gb + 1], gz = grid[gb + 2];
    float ix = ((gx + 1.f) * (float)WW - 1.f) * 0.5f;
    float iy = ((gy + 1.f) * (float)HH - 1.f) * 0.5f;
    float iz = ((gz + 1.f) * (float)DB - 1.f) * 0.5f;
    float xf = floorf(ix), yf = floorf(iy), zf = floorf(iz);
    float fx = ix - xf, fy = iy - yf, fz = iz - zf;
    int x0 = (int)xf, y0 = (int)yf, z0 = (int)zf;
    float wxa[2] = {1.f - fx, fx};
    float wya[2] = {1.f - fy, fy};
    float wza[2] = {1.f - fz, fz};
    #pragma unroll
    for (int dy2 = 0; dy2 < 2; ++dy2) {
      int y = y0 + dy2;
      bool vyb = (y >= 0) && (y < HH);
      int yc = y < 0 ? 0 : (y > HH - 1 ? HH - 1 : y);
      #pragma unroll
      for (int dx2 = 0; dx2 < 2; ++dx2) {
        int x = x0 + dx2;
        bool vxb = (x >= 0) && (x < WW);
        int xc = x < 0 ? 0 : (x > WW - 1 ? WW - 1 : x);
        float wxy = wxa[dx2] * wya[dy2];
        const f16* base = dp + ((long)((n * HH + yc) * WW + xc)) * DB;
        #pragma unroll
        for (int dz2 = 0; dz2 < 2; ++dz2) {
          int z = z0 + dz2;
          bool vzb = (z >= 0) && (z < DB);
          int zc = z < 0 ? 0 : (z > DB - 1 ? DB - 1 : z);
          float wgt = wxy * wza[dz2];
          if (vxb && vyb && vzb) {
            msk += wgt;
            agg += wgt * (float)base[zc];
          }
        }
      }
    }
  }
  out[v] = (msk > 0.f) ? (agg / msk) : agg;
}

extern "C" void kernel_launch(void* const* d_in, const int* in_sizes, int n_in,
                              void* d_out, int out_size, void* d_ws, size_t ws_size,
                              hipStream_t stream) {
  const float* img   = (const float*)d_in[0];
  const float* intr  = (const float*)d_in[1];
  const float* grid  = (const float*)d_in[2];
  const float* red_w = (const float*)d_in[3];
  const float* red_s = (const float*)d_in[4];
  const float* red_b = (const float*)d_in[5];
  const float* w1    = (const float*)d_in[6];
  const float* b1    = (const float*)d_in[7];
  const float* w2    = (const float*)d_in[8];
  const float* b2    = (const float*)d_in[9];
  const float* rw    = (const float*)d_in[10];
  const float* rb    = (const float*)d_in[11];
  const float* ew    = (const float*)d_in[12];
  const float* eb    = (const float*)d_in[13];
  const float* bb_w  = (const float*)d_in[14];
  const float* bb_s  = (const float*)d_in[15];
  const float* bb_b  = (const float*)d_in[16];
  const float* dp_w  = (const float*)d_in[17];
  const float* dp_b  = (const float*)d_in[18];
  float* out = (float*)d_out;

  char* ws = (char*)d_ws;
  float* gate = (float*)(ws + O_GATE);
  f16* wfred  = (f16*)(ws + O_WFRED);
  f16* wfbb   = (f16*)(ws + O_WFBB);
  f16* wfdp   = (f16*)(ws + O_WFDP);
  f16* xp0    = (f16*)(ws + O_XP0);
  f16* X1     = (f16*)(ws + O_X1);
  f16* X2     = (f16*)(ws + O_X2);
  f16* X3     = (f16*)(ws + O_X3);
  f16* dpb    = (f16*)(ws + O_DP);

  halo_zero_kernel<<<915, 256, 0, stream>>>(xp0, X1, X2, X3);
  {
    long per = 4L * 9 * 8 * 4096, total = per;
    wfrag_kernel<<<2048, 256, 0, stream>>>(red_w, red_s, wfred, 9, 512, 256, per, total);
  }
  {
    long per = 4L * 9 * 4 * 4096, total = 6 * per;
    wfrag_kernel<<<4096, 256, 0, stream>>>(bb_w, bb_s, wfbb, 9, 256, 256, per, total);
  }
  {
    long per = 2L * 1 * 4 * 4096, total = per;
    wfrag_kernel<<<128, 256, 0, stream>>>(dp_w, nullptr, wfdp, 1, 256, 112, per, total);
  }
  img_trans_kernel<<<dim3(48, 32, 6), 256, 0, stream>>>(img, xp0);
  se_gate_kernel<<<6, 256, 0, stream>>>(intr, w1, b1, w2, b2, rw, rb, ew, eb, gate);

  const long WCH = 4L * 9 * 4 * 4096;  // per-conv fragment-weight stride (f16)

  conv_mfma<0, 512, 9><<<528, 256, 0, stream>>>(xp0, wfred, red_b, gate, nullptr, X1, nullptr, 2);

  conv_mfma<1, 256, 9><<<528, 256, 0, stream>>>(X1, wfbb + 0 * WCH, bb_b + 0 * 256, nullptr, nullptr, X2, nullptr, 2);
  conv_mfma<2, 256, 9><<<528, 256, 0, stream>>>(X2, wfbb + 1 * WCH, bb_b + 1 * 256, nullptr, X1, X3, nullptr, 2);
  conv_mfma<1, 256, 9><<<528, 256, 0, stream>>>(X3, wfbb + 2 * WCH, bb_b + 2 * 256, nullptr, nullptr, X2, nullptr, 2);
  conv_mfma<2, 256, 9><<<528, 256, 0, stream>>>(X2, wfbb + 3 * WCH, bb_b + 3 * 256, nullptr, X3, X1, nullptr, 2);
  conv_mfma<1, 256, 9><<<528, 256, 0, stream>>>(X1, wfbb + 4 * WCH, bb_b + 4 * 256, nullptr, nullptr, X2, nullptr, 2);
  conv_mfma<2, 256, 9><<<528, 256, 0, stream>>>(X2, wfbb + 5 * WCH, bb_b + 5 * 256, nullptr, X1, X3, nullptr, 2);

  // depth 1x1 conv with fused softmax -> f16 dp
  conv_mfma<3, 256, 1><<<264, 256, 28928, stream>>>(X3, wfdp, dp_b, nullptr, nullptr, nullptr, dpb, 1);

  sample_kernel<<<1024, 256, 0, stream>>>(grid, dpb, out);
}

// Round 6
// 709.946 us; speedup vs baseline: 2.0108x; 1.9982x over previous
//
#include <hip/hip_runtime.h>

typedef _Float16 f16;
typedef _Float16 f16x8 __attribute__((ext_vector_type(8)));
typedef _Float16 f16x4 __attribute__((ext_vector_type(4)));
typedef float f32x4 __attribute__((ext_vector_type(4)));

#define NCAM 6
#define CINF 512
#define MIDC 256
#define DB   112
#define HH   32
#define WW   88
#define PH   34
#define PW   90
#define NPOS (HH*WW)       /* 2816 */
#define PT64 44            /* 64-pos tiles per cam; 264 ptiles = 8 XCD x 33 */

// ---- workspace layout (bytes) ----
#define O_GATE   0L
#define O_WFRED  6144L
#define O_WFBB   2365440L
#define O_WFDP   9443328L
#define O_XP0    9508864L
#define O_X1     28309504L
#define O_DP     28309504L    /* f16 dp overlays X1; written by depth conv after X1's last read */
#define O_X2     37709824L
#define O_X3     47110144L
/* end: 56510464 */

__device__ __forceinline__ void gl_lds16(const void* g, void* l) {
  __builtin_amdgcn_global_load_lds((const __attribute__((address_space(1))) void*)g,
                                   (__attribute__((address_space(3))) void*)l, 16, 0, 0);
}

// ---------------- halo-only zeroing of the 4 padded NHWC buffers ----------------
__global__ void halo_zero_kernel(f16* __restrict__ xp0, f16* __restrict__ X1,
                                 f16* __restrict__ X2, f16* __restrict__ X3) {
  int idx = blockIdx.x * 256 + threadIdx.x;       // one 16B chunk each
  f16* base; int C, rem;
  if (idx < 93696) { base = xp0; C = 512; rem = idx; }
  else {
    int k = idx - 93696;
    int bsel = k / 46848;
    if (bsel >= 3) return;
    rem = k - bsel * 46848; C = 256;
    base = (bsel == 0) ? X1 : (bsel == 1) ? X2 : X3;
  }
  int chunks = C >> 3;
  int cell = rem / chunks, cc = rem - cell * chunks;
  int cam = cell / 244, p = cell - cam * 244;
  int hh, ww;
  if (p < 90)       { hh = 0;  ww = p; }
  else if (p < 180) { hh = 33; ww = p - 90; }
  else { int q = p - 180; hh = 1 + (q >> 1); ww = (q & 1) * 89; }
  long o = ((long)(cam * PH + hh) * PW + ww) * C + cc * 8;
  f16x8 z = {0,0,0,0,0,0,0,0};
  *(f16x8*)(base + o) = z;
}

// ---------------- weights -> BK128 k-step-major A-fragment order, scale folded ----------------
// dst idx = (((((g*TAPS+tap)*CPT2+cc2)*4+ks)*64+lane)*4+mi)*8 + j
// co = g*64+mi*16+(lane&15), ci = cc2*128+ks*32+(lane>>4)*8+j, src OIHW[co][ci][tap]
// -> per (chunk,ks): lane's 4 mi-fragments are 64B contiguous
__global__ void wfrag_kernel(const float* __restrict__ src, const float* __restrict__ scale,
                             f16* __restrict__ dst, int TAPS, int CI, int CO_SRC,
                             long per, long total) {
  long i0 = (long)blockIdx.x * blockDim.x + threadIdx.x;
  long stride = (long)gridDim.x * blockDim.x;
  int CPT2 = CI >> 7;
  for (long i = i0; i < total; i += stride) {
    int conv = (int)(i / per);
    long rem = i - (long)conv * per;
    int j = (int)(rem & 7);
    int mi = (int)((rem >> 3) & 3);
    int lane = (int)((rem >> 5) & 63);
    int ks = (int)((rem >> 11) & 3);
    long b = rem >> 13;
    int cc2 = (int)(b % CPT2);
    long b2 = b / CPT2;
    int tap = (int)(b2 % TAPS);
    int g = (int)(b2 / TAPS);
    int co = g * 64 + mi * 16 + (lane & 15);
    int ci = cc2 * 128 + ks * 32 + (lane >> 4) * 8 + j;
    float v = 0.f;
    if (co < CO_SRC) {
      v = src[(long)conv * CO_SRC * CI * TAPS + ((long)co * CI + ci) * TAPS + tap];
      if (scale) v *= scale[conv * CO_SRC + co];
    }
    dst[i] = (f16)v;
  }
}

// ---------------- img NCHW f32 -> padded NHWC f16 ----------------
__global__ void img_trans_kernel(const float* __restrict__ src, f16* __restrict__ dst) {
  __shared__ float tile[32][33];
  int tx = threadIdx.x & 31, ty = threadIdx.x >> 5;
  int wt = blockIdx.x % 3, ct = blockIdx.x / 3;
  int h = blockIdx.y, n = blockIdx.z;
  int w0 = wt * 32, c0 = ct * 32;
  #pragma unroll
  for (int i = 0; i < 4; ++i) {
    int cl = ty + i * 8;
    int w = w0 + tx;
    float v = 0.f;
    if (w < WW) v = src[((long)(n * CINF + c0 + cl) * HH + h) * WW + w];
    tile[cl][tx] = v;
  }
  __syncthreads();
  #pragma unroll
  for (int i = 0; i < 4; ++i) {
    int wl = ty + i * 8;
    int w = w0 + wl;
    if (w < WW)
      dst[((long)((n * PH + h + 1) * PW + (w + 1))) * CINF + c0 + tx] = (f16)tile[tx][wl];
  }
}

// ---------------- SE gate ----------------
__global__ void se_gate_kernel(const float* __restrict__ intr,
                               const float* __restrict__ w1, const float* __restrict__ b1,
                               const float* __restrict__ w2, const float* __restrict__ b2,
                               const float* __restrict__ rw, const float* __restrict__ rb,
                               const float* __restrict__ ew, const float* __restrict__ eb,
                               float* __restrict__ gate) {
  __shared__ float sps;
  __shared__ float h1[MIDC];
  __shared__ float h2[MIDC];
  __shared__ float tt[MIDC];
  int n = blockIdx.x, c = threadIdx.x;
  if (c == 0) {
    float a[4][8];
    for (int i = 0; i < 4; ++i)
      for (int j = 0; j < 4; ++j) {
        a[i][j] = intr[n * 16 + i * 4 + j];
        a[i][4 + j] = (i == j) ? 1.f : 0.f;
      }
    for (int col = 0; col < 4; ++col) {
      int piv = col;
      for (int r2 = col + 1; r2 < 4; ++r2)
        if (fabsf(a[r2][col]) > fabsf(a[piv][col])) piv = r2;
      if (piv != col)
        for (int j = 0; j < 8; ++j) { float tv = a[col][j]; a[col][j] = a[piv][j]; a[piv][j] = tv; }
      float invp = 1.f / a[col][col];
      for (int j = 0; j < 8; ++j) a[col][j] *= invp;
      for (int r2 = 0; r2 < 4; ++r2)
        if (r2 != col) {
          float f = a[r2][col];
          for (int j = 0; j < 8; ++j) a[r2][j] -= f * a[col][j];
        }
    }
    float i00 = a[0][4], i11 = a[1][5];
    sps = sqrtf(i00 * i00 + i11 * i11) * 1000.f;
  }
  __syncthreads();
  float sp = sps;
  h1[c] = fmaxf(sp * w1[c] + b1[c], 0.f);
  __syncthreads();
  float acc = b2[c];
  for (int j = 0; j < MIDC; ++j) acc += h1[j] * w2[j * MIDC + c];
  h2[c] = acc;
  __syncthreads();
  acc = rb[c];
  for (int j = 0; j < MIDC; ++j) acc += rw[c * MIDC + j] * h2[j];
  tt[c] = fmaxf(acc, 0.f);
  __syncthreads();
  acc = eb[c];
  for (int j = 0; j < MIDC; ++j) acc += ew[c * MIDC + j] * tt[j];
  gate[n * MIDC + c] = 1.f / (1.f + expf(-acc));
}

// ---------------- MFMA implicit-GEMM conv v6: BK=128, 32 MFMA per single barrier ----------------
// Tile 128co x 64pos, 4 waves (wm co-half, wn pos-half), wave 64co x 32pos.
// K-loop per 128-ci chunk: __syncthreads (drains DMA issued a full chunk ago ->
// cheap), issue next chunk's DMA (16KB via 16x global_load_lds_dwordx4,
// XOR-swizzled), then 4 k-steps x (4 A dwordx4 loads + 2 ds_read_b128 + 8 MFMA).
// A streams global->VGPR inside the region (compiler emits interleaved vmcnt(N)).
// XCD swizzle keeps FETCH ~20MB (R4-proven). MODE 0: relu(+b)*gate; 1: relu(+b);
// 2: relu(+b+res); 3: depth logits + fused softmax -> f16 dp.
template<int MODE, int CIN_T, int TAPS>
__global__ __launch_bounds__(256, 3)
void conv_mfma(const f16* __restrict__ X, const f16* __restrict__ Wf,
               const float* __restrict__ bias, const float* __restrict__ gate,
               const f16* __restrict__ res, f16* __restrict__ Yf16,
               f16* __restrict__ dpout) {
  constexpr int CPT2 = CIN_T / 128;   // 128-ci chunks per tap (4 or 2)
  constexpr int NCH = TAPS * CPT2;    // 36 / 18 / 2
  extern __shared__ __align__(16) char smem[];   // 2 x 16KB B buffers (+MODE3 Lt reuse)

  const int t = threadIdx.x;
  const int wv = t >> 6, ln = t & 63, lm = ln & 15, quad = ln >> 4;
  const int wm = wv >> 1, wn = wv & 1;

  // XCD-aware swizzle: ptiles sliced 8 x 33
  const int bid = blockIdx.x;
  const int xcd = bid & 7;
  const int li = bid >> 3;
  const int co_tile = li / 33;
  const int lp = li - co_tile * 33;
  const int ptile = xcd * 33 + lp;
  const int cam = ptile / PT64;
  const int pbase = (ptile % PT64) * 64;

  // B DMA pointers: 4 instr/wave (j), instruction index i = j*4+wv covers rows 4i..4i+3
  const f16* gB[4];
  #pragma unroll
  for (int j = 0; j < 4; ++j) {
    int i = j * 4 + wv;
    int r = i * 4 + (ln >> 4);
    int pos = pbase + r;
    int hh = pos / WW, w2 = pos - hh * WW;
    int col8 = (ln & 15) ^ ((i & 1) * 4 + (ln >> 4));   // phys->logical slot unswizzle
    gB[j] = X + ((long)((cam * PH + hh + 1) * PW + (w2 + 1))) * CIN_T + col8 * 8;
  }
  // A stream base for this wave's 64-co group
  const int g = co_tile * 2 + wm;
  const f16* wa = Wf + (long)g * TAPS * CPT2 * 8192;

  const int brow = (wn * 32 + lm) * 256;   // LDS byte offset of this lane's row

  f32x4 acc[4][2];
  #pragma unroll
  for (int mi = 0; mi < 4; ++mi)
    #pragma unroll
    for (int ni = 0; ni < 2; ++ni)
      #pragma unroll
      for (int r = 0; r < 4; ++r) acc[mi][ni][r] = 0.f;

  auto choff = [&](int c) -> int {
    int tap = c / CPT2, cc = c - (c / CPT2) * CPT2;
    int dy = (TAPS == 9) ? (tap / 3 - 1) : 0;
    int dx = (TAPS == 9) ? (tap % 3 - 1) : 0;
    return (dy * PW + dx) * CIN_T + cc * 128;
  };
  auto dmaf = [&](int bsel, int off) {
    #pragma unroll
    for (int j = 0; j < 4; ++j) {
      int i = j * 4 + wv;
      gl_lds16(gB[j] + off, smem + bsel * 16384 + i * 1024);
    }
  };

  dmaf(0, choff(0));

  #pragma unroll 1
  for (int c = 0; c < NCH; ++c) {
    const int cur = c & 1;
    __syncthreads();                       // drains chunk-c DMA (issued ~1 chunk ago)
    if (c + 1 < NCH) dmaf(cur ^ 1, choff(c + 1));
    const f16* ap = wa + (long)c * 8192 + ln * 32;
    const char* bb = smem + cur * 16384 + brow;
    #pragma unroll
    for (int ks = 0; ks < 4; ++ks) {
      f16x8 a[4], bf[2];
      #pragma unroll
      for (int mi = 0; mi < 4; ++mi)
        a[mi] = *(const f16x8*)(ap + ks * 2048 + mi * 8);
      const int sx = ((ks * 4 + quad) ^ (lm & 7)) * 16;
      #pragma unroll
      for (int ni = 0; ni < 2; ++ni)
        bf[ni] = *(const f16x8*)(bb + ni * 4096 + sx);
      #pragma unroll
      for (int mi = 0; mi < 4; ++mi)
        #pragma unroll
        for (int ni = 0; ni < 2; ++ni)
          acc[mi][ni] = __builtin_amdgcn_mfma_f32_16x16x32_f16(a[mi], bf[ni], acc[mi][ni], 0, 0, 0);
    }
  }

  if (MODE == 3) {
    // ---- fused bias + softmax over 112 bins -> f16 dp ----
    __syncthreads();                                   // Lt aliases B buffers
    float* Lt = (float*)smem;                          // [64][113] f32
    #pragma unroll
    for (int mi = 0; mi < 4; ++mi) {
      int co_l = wm * 64 + mi * 16 + quad * 4;
      if (co_l >= DB) continue;                        // skips only (wm=1,mi=3)
      float4 b4 = *(const float4*)(bias + co_l);
      #pragma unroll
      for (int ni = 0; ni < 2; ++ni) {
        int pl = wn * 32 + ni * 16 + lm;
        #pragma unroll
        for (int r = 0; r < 4; ++r)
          Lt[pl * 113 + co_l + r] = acc[mi][ni][r] + ((float*)&b4)[r];
      }
    }
    __syncthreads();
    int p = t >> 2, q = t & 3;
    const float* rowp = Lt + p * 113 + q * 28;
    float m = -1e30f;
    #pragma unroll
    for (int i = 0; i < 28; ++i) m = fmaxf(m, rowp[i]);
    m = fmaxf(m, __shfl_xor(m, 1));
    m = fmaxf(m, __shfl_xor(m, 2));
    float e[28], ssum = 0.f;
    #pragma unroll
    for (int i = 0; i < 28; ++i) { e[i] = __expf(rowp[i] - m); ssum += e[i]; }
    ssum += __shfl_xor(ssum, 1);
    ssum += __shfl_xor(ssum, 2);
    float inv = 1.f / ssum;
    f16* o = dpout + ((long)(cam * NPOS + pbase + p)) * DB + q * 28;
    #pragma unroll
    for (int i = 0; i < 28; ++i) o[i] = (f16)(e[i] * inv);
    return;
  }

  // ---- epilogue: direct stores from acc ----
  float4 b4[4], g4[4];
  #pragma unroll
  for (int mi = 0; mi < 4; ++mi) {
    int co_g = co_tile * 128 + wm * 64 + mi * 16 + quad * 4;
    b4[mi] = *(const float4*)(bias + co_g);
    if (MODE == 0) g4[mi] = *(const float4*)(gate + cam * MIDC + co_g);
  }
  #pragma unroll
  for (int ni = 0; ni < 2; ++ni) {
    int pos = pbase + wn * 32 + ni * 16 + lm;
    int hh = pos / WW, w2 = pos - hh * WW;
    long ob = ((long)((cam * PH + hh + 1) * PW + (w2 + 1))) * MIDC + co_tile * 128;
    #pragma unroll
    for (int mi = 0; mi < 4; ++mi) {
      int co_l = wm * 64 + mi * 16 + quad * 4;
      float v[4];
      #pragma unroll
      for (int r = 0; r < 4; ++r) {
        float y = acc[mi][ni][r] + ((float*)&b4[mi])[r];
        if (MODE == 0) y = fmaxf(y, 0.f) * ((float*)&g4[mi])[r];
        else if (MODE == 1) y = fmaxf(y, 0.f);
        v[r] = y;
      }
      if (MODE == 2) {
        f16x4 rv = *(const f16x4*)(res + ob + co_l);
        f16x4 o;
        #pragma unroll
        for (int r = 0; r < 4; ++r) o[r] = (f16)fmaxf(v[r] + (float)rv[r], 0.f);
        *(f16x4*)(Yf16 + ob + co_l) = o;
      } else {
        f16x4 o;
        #pragma unroll
        for (int r = 0; r < 4; ++r) o[r] = (f16)v[r];
        *(f16x4*)(Yf16 + ob + co_l) = o;
      }
    }
  }
}

// ---------------- trilinear grid sample (f16 dp), cams fully unrolled for MLP ----------------
__global__ __launch_bounds__(256, 2)
void sample_kernel(const float* __restrict__ grid, const f16* __restrict__ dp,
                   float* __restrict__ out) {
  int v = blockIdx.x * blockDim.x + threadIdx.x;     // grid is exact (1024*256)
  int vz = v & 15, vy = (v >> 4) & 127, vx = v >> 11;
  float agg = 0.f, msk = 0.f;
  #pragma unroll
  for (int n = 0; n < NCAM; ++n) {
    long gb = ((long)((n * 128 + vx) * 128 + vy) * 16 + vz) * 3;
    float gx = grid[gb], gy = grid[gb + 1], gz = grid[gb + 2];
    float ix = ((gx + 1.f) * (float)WW - 1.f) * 0.5f;
    float iy = ((gy + 1.f) * (float)HH - 1.f) * 0.5f;
    float iz = ((gz + 1.f) * (float)DB - 1.f) * 0.5f;
    float xf = floorf(ix), yf = floorf(iy), zf = floorf(iz);
    float fx = ix - xf, fy = iy - yf, fz = iz - zf;
    int x0 = (int)xf, y0 = (int)yf, z0 = (int)zf;
    float wxa[2] = {1.f - fx, fx};
    float wya[2] = {1.f - fy, fy};
    float wza[2] = {1.f - fz, fz};
    #pragma unroll
    for (int dy2 = 0; dy2 < 2; ++dy2) {
      int y = y0 + dy2;
      bool vyb = (y >= 0) && (y < HH);
      int yc = y < 0 ? 0 : (y > HH - 1 ? HH - 1 : y);
      #pragma unroll
      for (int dx2 = 0; dx2 < 2; ++dx2) {
        int x = x0 + dx2;
        bool vxb = (x >= 0) && (x < WW);
        int xc = x < 0 ? 0 : (x > WW - 1 ? WW - 1 : x);
        float wxy = wxa[dx2] * wya[dy2];
        const f16* base = dp + ((long)((n * HH + yc) * WW + xc)) * DB;
        #pragma unroll
        for (int dz2 = 0; dz2 < 2; ++dz2) {
          int z = z0 + dz2;
          bool vzb = (z >= 0) && (z < DB);
          int zc = z < 0 ? 0 : (z > DB - 1 ? DB - 1 : z);
          float wgt = wxy * wza[dz2];
          float mm = (vxb && vyb && vzb) ? wgt : 0.f;
          float d = (float)base[zc];
          msk += mm;
          agg += mm * d;
        }
      }
    }
  }
  out[v] = (msk > 0.f) ? (agg / msk) : agg;
}

extern "C" void kernel_launch(void* const* d_in, const int* in_sizes, int n_in,
                              void* d_out, int out_size, void* d_ws, size_t ws_size,
                              hipStream_t stream) {
  const float* img   = (const float*)d_in[0];
  const float* intr  = (const float*)d_in[1];
  const float* grid  = (const float*)d_in[2];
  const float* red_w = (const float*)d_in[3];
  const float* red_s = (const float*)d_in[4];
  const float* red_b = (const float*)d_in[5];
  const float* w1    = (const float*)d_in[6];
  const float* b1    = (const float*)d_in[7];
  const float* w2    = (const float*)d_in[8];
  const float* b2    = (const float*)d_in[9];
  const float* rw    = (const float*)d_in[10];
  const float* rb    = (const float*)d_in[11];
  const float* ew    = (const float*)d_in[12];
  const float* eb    = (const float*)d_in[13];
  const float* bb_w  = (const float*)d_in[14];
  const float* bb_s  = (const float*)d_in[15];
  const float* bb_b  = (const float*)d_in[16];
  const float* dp_w  = (const float*)d_in[17];
  const float* dp_b  = (const float*)d_in[18];
  float* out = (float*)d_out;

  char* ws = (char*)d_ws;
  float* gate = (float*)(ws + O_GATE);
  f16* wfred  = (f16*)(ws + O_WFRED);
  f16* wfbb   = (f16*)(ws + O_WFBB);
  f16* wfdp   = (f16*)(ws + O_WFDP);
  f16* xp0    = (f16*)(ws + O_XP0);
  f16* X1     = (f16*)(ws + O_X1);
  f16* X2     = (f16*)(ws + O_X2);
  f16* X3     = (f16*)(ws + O_X3);
  f16* dpb    = (f16*)(ws + O_DP);

  halo_zero_kernel<<<915, 256, 0, stream>>>(xp0, X1, X2, X3);
  {
    long per = 4L * 9 * 4 * 8192, total = per;            // 1,179,648
    wfrag_kernel<<<4608, 256, 0, stream>>>(red_w, red_s, wfred, 9, 512, 256, per, total);
  }
  {
    long per = 4L * 9 * 2 * 8192, total = 6 * per;        // 6 x 589,824
    wfrag_kernel<<<6912, 256, 0, stream>>>(bb_w, bb_s, wfbb, 9, 256, 256, per, total);
  }
  {
    long per = 2L * 1 * 2 * 8192, total = per;            // 32,768
    wfrag_kernel<<<128, 256, 0, stream>>>(dp_w, nullptr, wfdp, 1, 256, 112, per, total);
  }
  img_trans_kernel<<<dim3(48, 32, 6), 256, 0, stream>>>(img, xp0);
  se_gate_kernel<<<6, 256, 0, stream>>>(intr, w1, b1, w2, b2, rw, rb, ew, eb, gate);

  const long WCH = 4L * 9 * 2 * 8192;  // per-conv fragment-weight stride (f16)

  conv_mfma<0, 512, 9><<<528, 256, 32768, stream>>>(xp0, wfred, red_b, gate, nullptr, X1, nullptr);

  conv_mfma<1, 256, 9><<<528, 256, 32768, stream>>>(X1, wfbb + 0 * WCH, bb_b + 0 * 256, nullptr, nullptr, X2, nullptr);
  conv_mfma<2, 256, 9><<<528, 256, 32768, stream>>>(X2, wfbb + 1 * WCH, bb_b + 1 * 256, nullptr, X1, X3, nullptr);
  conv_mfma<1, 256, 9><<<528, 256, 32768, stream>>>(X3, wfbb + 2 * WCH, bb_b + 2 * 256, nullptr, nullptr, X2, nullptr);
  conv_mfma<2, 256, 9><<<528, 256, 32768, stream>>>(X2, wfbb + 3 * WCH, bb_b + 3 * 256, nullptr, X3, X1, nullptr);
  conv_mfma<1, 256, 9><<<528, 256, 32768, stream>>>(X1, wfbb + 4 * WCH, bb_b + 4 * 256, nullptr, nullptr, X2, nullptr);
  conv_mfma<2, 256, 9><<<528, 256, 32768, stream>>>(X2, wfbb + 5 * WCH, bb_b + 5 * 256, nullptr, X1, X3, nullptr);

  // depth 1x1 conv with fused softmax -> f16 dp
  conv_mfma<3, 256, 1><<<264, 256, 32768, stream>>>(X3, wfdp, dp_b, nullptr, nullptr, nullptr, dpb);

  sample_kernel<<<1024, 256, 0, stream>>>(grid, dpb, out);
}